// Round 7
// baseline (772.888 us; speedup 1.0000x reference)
//
#include <hip/hip_runtime.h>
#include <stdint.h>

// Problem dims
#define NB  256
#define NT  100
#define NIN 128
#define NH  1024
#define NOUT 35

// d_out float offsets
#define O_SPK2 26214400ull
#define O_SPK3 52428800ull
#define O_SPK4 78643200ull
#define O_MEM4 79539200ull

// d_ws byte offsets (regions reused; k2/k3/k4 now nibble-packed, smaller)
#define WS_XT   0ull          // 25600*128*4 = 13107200
#define WS_Q1T  13107200ull   // 131072*4 = 524288
#define WS_K2T  13631488ull   // nibble: 1024*512 = 524288
#define WS_K3T  14680064ull   // nibble: 524288
#define WS_K4T  15728640ull   // nibble: 1024*24 = 24576

// scale = (w_max - w_min)/15 computed in python fp64 then cast to fp32
#define S2C ((float)((1.0 - 0.001) / 15.0))
#define S1C ((float)(1.0 / 15.0))

__device__ __forceinline__ uint32_t kq(float wv) {
  float wc = fminf(fmaxf(wv, 0.001f), 1.0f);
  return (uint32_t)(int)rintf((wc - 0.001f) / S2C);
}

// ------------------------------------------------------------------
// K1: quantize weights -> nibble-packed transposed matrices + q1T + xt
// ------------------------------------------------------------------
__global__ void k_prep(const float* __restrict__ x, const float* __restrict__ w1,
                       const float* __restrict__ w2, const float* __restrict__ w3,
                       const float* __restrict__ w4, uint8_t* __restrict__ ws)
{
  long long id = (long long)blockIdx.x * 256 + threadIdx.x;
  if (id < 524288) {                        // k2P[i*512+jp] = k(w2[2jp][i]) | k(w2[2jp+1][i])<<4
    int i = (int)(id >> 9), jp = (int)(id & 511);
    uint32_t ka = kq(w2[(size_t)(2 * jp) * 1024 + i]);
    uint32_t kb = kq(w2[(size_t)(2 * jp + 1) * 1024 + i]);
    ws[WS_K2T + id] = (uint8_t)(ka | (kb << 4));
    return;
  }
  id -= 524288;
  if (id < 524288) {                        // k3P
    int i = (int)(id >> 9), jp = (int)(id & 511);
    uint32_t ka = kq(w3[(size_t)(2 * jp) * 1024 + i]);
    uint32_t kb = kq(w3[(size_t)(2 * jp + 1) * 1024 + i]);
    ws[WS_K3T + id] = (uint8_t)(ka | (kb << 4));
    return;
  }
  id -= 524288;
  if (id < 24576) {                         // k4P stride 24B, pad j>=35 with 0
    int i = (int)(id / 24), bp = (int)(id % 24);
    int j0 = 2 * bp, j1 = 2 * bp + 1;
    uint32_t ka = (j0 < NOUT) ? kq(w4[(size_t)j0 * 1024 + i]) : 0u;
    uint32_t kb = (j1 < NOUT) ? kq(w4[(size_t)j1 * 1024 + i]) : 0u;
    ws[WS_K4T + id] = (uint8_t)(ka | (kb << 4));
    return;
  }
  id -= 24576;
  if (id < 131072) {                        // q1T[i*1024+j] = fake_quant(w1[j][i]) fp32
    int i = (int)(id >> 10), j = (int)(id & 1023);
    float wv = w1[(size_t)j * 128 + i];
    float wc = fminf(fmaxf(wv, -0.5f), 0.5f);
    float q = rintf((wc + 0.5f) / S1C) * S1C - 0.5f;
    ((float*)(ws + WS_Q1T))[id] = q;
    return;
  }
  id -= 131072;
  if (id < 3276800) {                       // xt[(t*256+b)*128+i] = x[b][t][i]/15
    int row = (int)(id >> 7), i = (int)(id & 127);
    int tt = row >> 8, bb = row & 255;
    ((float*)(ws + WS_XT))[id] = x[((size_t)bb * NT + tt) * NIN + i] / 15.0f;
  }
}

// ------------------------------------------------------------------
// K2: fused layer-1 GEMM + LIF scan, LDS-staged x (R2-proven math),
// re-tiled to 256 threads x 4 neurons: halves per-CU ds_read count
// (the measured 124us was LDS-pipe bound: 8 waves x 3200 b128 x 12cy).
// FMA chain per neuron is ascending-i, bitwise identical.
// ------------------------------------------------------------------
__global__ __launch_bounds__(256, 1) void k_spk1(const float* __restrict__ xt,
                                                 const float* __restrict__ q1T,
                                                 float* __restrict__ out)
{
  __shared__ float xs[25 * 128];        // [tt][i], 12.8 KB
  const int b = blockIdx.x;
  const int tid = threadIdx.x;          // 0..255
  float m[4] = {0.f, 0.f, 0.f, 0.f};

  for (int c = 0; c < 4; ++c) {
    __syncthreads();                    // xs reuse guard
    #pragma unroll
    for (int k = 0; k < 4; ++k) {       // stage 800 float4
      int e = tid + k * 256;
      if (e < 800) {
        int tt = e >> 5, iq = e & 31;
        ((float4*)xs)[e] = *(const float4*)(xt + ((size_t)(c * 25 + tt) * NB + b) * NIN + iq * 4);
      }
    }
    __syncthreads();

    float acc[4][25];
    #pragma unroll
    for (int tt = 0; tt < 25; ++tt) {
      acc[0][tt] = 0.f; acc[1][tt] = 0.f; acc[2][tt] = 0.f; acc[3][tt] = 0.f;
    }
    for (int ib = 0; ib < 16; ++ib) {   // rolled: small I$
      float q0[8], q1v[8], q2v[8], q3v[8];
      #pragma unroll
      for (int u = 0; u < 8; ++u) {
        const float* qp = q1T + (size_t)(ib * 8 + u) * NH + tid;
        q0[u]  = qp[0];
        q1v[u] = qp[256];
        q2v[u] = qp[512];
        q3v[u] = qp[768];
      }
      #pragma unroll
      for (int tt = 0; tt < 25; ++tt) {
        const float4 xa = *(const float4*)&xs[tt * 128 + ib * 8];
        const float4 xb = *(const float4*)&xs[tt * 128 + ib * 8 + 4];
        float xr[8] = {xa.x, xa.y, xa.z, xa.w, xb.x, xb.y, xb.z, xb.w};
        #pragma unroll
        for (int u = 0; u < 8; ++u) {
          acc[0][tt] = fmaf(xr[u], q0[u],  acc[0][tt]);
          acc[1][tt] = fmaf(xr[u], q1v[u], acc[1][tt]);
          acc[2][tt] = fmaf(xr[u], q2v[u], acc[2][tt]);
          acc[3][tt] = fmaf(xr[u], q3v[u], acc[3][tt]);
        }
      }
    }
    // sequential LIF scan (subtract-reset), identical math/order
    #pragma unroll
    for (int tt = 0; tt < 25; ++tt) {
      const int t = c * 25 + tt;
      const size_t row = ((size_t)t * NB + b) * (size_t)NH;
      #pragma unroll
      for (int n = 0; n < 4; ++n) {
        float rst = m[n] > 1.0f ? 1.0f : 0.0f;
        m[n] = fmaf(0.9f, m[n], acc[n][tt]) - rst;
        out[row + n * 256 + tid] = ((m[n] - 1.0f) > 0.0f) ? 1.0f : 0.0f;
      }
    }
  }
}

// ------------------------------------------------------------------
// K3: persistent per-batch-element SNN loop (R6 512-thread structure)
// with NIBBLE-PACKED gathers: dwordx2 per row (half L2 bytes), 4
// mask-planes of u16-pair accumulation. Exact integer math.
// acc[q][r] fields = neurons {l*16+q*8+r, l*16+q*8+r+4}.
// ------------------------------------------------------------------
#define ACCN(V) do { \
  a00 += (V).x & 0x000F000Fu; a01 += ((V).x >> 4) & 0x000F000Fu; \
  a02 += ((V).x >> 8) & 0x000F000Fu; a03 += ((V).x >> 12) & 0x000F000Fu; \
  a10 += (V).y & 0x000F000Fu; a11 += ((V).y >> 4) & 0x000F000Fu; \
  a12 += ((V).y >> 8) & 0x000F000Fu; a13 += ((V).y >> 12) & 0x000F000Fu; } while (0)

__global__ __launch_bounds__(512, 1) void k_main(
    const uint8_t* __restrict__ k2P, const uint8_t* __restrict__ k3P,
    const uint8_t* __restrict__ k4P, float* __restrict__ out)
{
  const int b = blockIdx.x;
  const int tid = threadIdx.x;
  const int lane = tid & 63;
  const int wave = tid >> 6;            // 8 gather groups

  __shared__ uint16_t list[1024];
  __shared__ uint4    pEa4[512];        // [g<8][lane*4+r]: acc[0][r] (u16 pair)
  __shared__ uint4    pOa4[512];        // acc[1][r]
  __shared__ uint4    wcnt4[2];
  uint32_t* pEa  = (uint32_t*)pEa4;
  uint32_t* pOa  = (uint32_t*)pOa4;
  uint32_t* wcnt = (uint32_t*)wcnt4;

  float m2[2] = {0.f, 0.f}, m3[2] = {0.f, 0.f}, m4 = 0.f;
  uint32_t nT, nL; bool cm;

  // atomic-free list build: register prefix over per-wave counts
  auto buildList = [&](uint64_t bA, uint64_t bB) {
    const uint4 c0 = wcnt4[0], c1 = wcnt4[1];
    nT = c0.x + c0.y + c0.z + c0.w + c1.x + c1.y + c1.z + c1.w;
    cm = nT > 512;
    nL = cm ? (1024u - nT) : nT;
    uint32_t pre = 0;
    pre += (wave > 0) ? c0.x : 0u;  pre += (wave > 1) ? c0.y : 0u;
    pre += (wave > 2) ? c0.z : 0u;  pre += (wave > 3) ? c0.w : 0u;
    pre += (wave > 4) ? c1.x : 0u;  pre += (wave > 5) ? c1.y : 0u;
    pre += (wave > 6) ? c1.z : 0u;
    const uint32_t bs = cm ? ((uint32_t)(wave << 7) - pre) : pre;
    const uint64_t cA = cm ? ~bA : bA;
    const uint64_t cB = cm ? ~bB : bB;
    const uint64_t ltm = (1ull << lane) - 1ull;
    if ((cA >> lane) & 1ull)
      list[bs + (uint32_t)__popcll(cA & ltm)] = (uint16_t)tid;
    if ((cB >> lane) & 1ull)
      list[bs + (uint32_t)__popcll(cA) + (uint32_t)__popcll(cB & ltm)] = (uint16_t)(tid + 512);
  };

  auto gatherBig = [&](const uint8_t* __restrict__ mat, uint32_t nLv) {
    uint32_t a00=0,a01=0,a02=0,a03=0,a10=0,a11=0,a12=0,a13=0;
    const uint8_t* bp = mat + (lane << 3);   // 64 lanes x 8B = full 512B row
    uint32_t a = (uint32_t)wave;
    for (; a + 24 < nLv; a += 32) {          // 4 loads in flight
      uint32_t i0 = (uint32_t)__builtin_amdgcn_readfirstlane((int)list[a]);
      uint32_t i1 = (uint32_t)__builtin_amdgcn_readfirstlane((int)list[a + 8]);
      uint32_t i2 = (uint32_t)__builtin_amdgcn_readfirstlane((int)list[a + 16]);
      uint32_t i3 = (uint32_t)__builtin_amdgcn_readfirstlane((int)list[a + 24]);
      const uint2 v0 = *(const uint2*)(bp + ((size_t)i0 << 9));
      const uint2 v1 = *(const uint2*)(bp + ((size_t)i1 << 9));
      const uint2 v2 = *(const uint2*)(bp + ((size_t)i2 << 9));
      const uint2 v3 = *(const uint2*)(bp + ((size_t)i3 << 9));
      ACCN(v0); ACCN(v1); ACCN(v2); ACCN(v3);
    }
    for (; a < nLv; a += 8) {
      uint32_t i0 = (uint32_t)__builtin_amdgcn_readfirstlane((int)list[a]);
      const uint2 v0 = *(const uint2*)(bp + ((size_t)i0 << 9));
      ACCN(v0);
    }
    const int basei = (wave << 8) + (lane << 2);
    *(uint4*)&pEa[basei] = make_uint4(a00, a01, a02, a03);
    *(uint4*)&pOa[basei] = make_uint4(a10, a11, a12, a13);
  };

  auto gatherAll = [&](const uint8_t* __restrict__ mat) {   // all 1024 rows
    uint32_t a00=0,a01=0,a02=0,a03=0,a10=0,a11=0,a12=0,a13=0;
    const uint8_t* bp = mat + (lane << 3);
    for (uint32_t a = (uint32_t)wave; a + 24 < 1024u; a += 32) {
      const uint2 v0 = *(const uint2*)(bp + ((size_t)a << 9));
      const uint2 v1 = *(const uint2*)(bp + ((size_t)(a + 8) << 9));
      const uint2 v2 = *(const uint2*)(bp + ((size_t)(a + 16) << 9));
      const uint2 v3 = *(const uint2*)(bp + ((size_t)(a + 24) << 9));
      ACCN(v0); ACCN(v1); ACCN(v2); ACCN(v3);
    }
    const int basei = (wave << 8) + (lane << 2);
    *(uint4*)&pEa[basei] = make_uint4(a00, a01, a02, a03);
    *(uint4*)&pOa[basei] = make_uint4(a10, a11, a12, a13);
  };

  auto gather4 = [&](uint32_t nLv) {         // k4P, 24-B rows, lanes 0..2
    uint32_t a00=0,a01=0,a02=0,a03=0,a10=0,a11=0,a12=0,a13=0;
    const uint8_t* bp = k4P + (lane << 3);
    uint32_t a = (uint32_t)wave;
    for (; a + 24 < nLv; a += 32) {
      uint32_t i0 = (uint32_t)__builtin_amdgcn_readfirstlane((int)list[a]);
      uint32_t i1 = (uint32_t)__builtin_amdgcn_readfirstlane((int)list[a + 8]);
      uint32_t i2 = (uint32_t)__builtin_amdgcn_readfirstlane((int)list[a + 16]);
      uint32_t i3 = (uint32_t)__builtin_amdgcn_readfirstlane((int)list[a + 24]);
      const uint2 v0 = *(const uint2*)(bp + (size_t)i0 * 24u);
      const uint2 v1 = *(const uint2*)(bp + (size_t)i1 * 24u);
      const uint2 v2 = *(const uint2*)(bp + (size_t)i2 * 24u);
      const uint2 v3 = *(const uint2*)(bp + (size_t)i3 * 24u);
      ACCN(v0); ACCN(v1); ACCN(v2); ACCN(v3);
    }
    for (; a < nLv; a += 8) {
      uint32_t i0 = (uint32_t)__builtin_amdgcn_readfirstlane((int)list[a]);
      const uint2 v0 = *(const uint2*)(bp + (size_t)i0 * 24u);
      ACCN(v0);
    }
    const int basei = (wave << 8) + (lane << 2);
    *(uint4*)&pEa[basei] = make_uint4(a00, a01, a02, a03);
    *(uint4*)&pOa[basei] = make_uint4(a10, a11, a12, a13);
  };

  auto gather4All = [&]() {
    uint32_t a00=0,a01=0,a02=0,a03=0,a10=0,a11=0,a12=0,a13=0;
    const uint8_t* bp = k4P + (lane << 3);
    for (uint32_t a = (uint32_t)wave; a + 24 < 1024u; a += 32) {
      const uint2 v0 = *(const uint2*)(bp + (size_t)a * 24u);
      const uint2 v1 = *(const uint2*)(bp + (size_t)(a + 8) * 24u);
      const uint2 v2 = *(const uint2*)(bp + (size_t)(a + 16) * 24u);
      const uint2 v3 = *(const uint2*)(bp + (size_t)(a + 24) * 24u);
      ACCN(v0); ACCN(v1); ACCN(v2); ACCN(v3);
    }
    const int basei = (wave << 8) + (lane << 2);
    *(uint4*)&pEa[basei] = make_uint4(a00, a01, a02, a03);
    *(uint4*)&pOa[basei] = make_uint4(a10, a11, a12, a13);
  };

  // nibble-plane partial sum decode: neuron j -> lane j>>4, u32 q=(j>>3)&1,
  // plane r=j&3, half hi=(j>>2)&1. Fields can't carry: max 15*1024 < 2^16.
  auto gsum = [&](int jn) -> uint32_t {
    const int idx = ((jn >> 4) << 2) + (jn & 3);
    const int sh = ((jn >> 2) & 1) << 4;
    const uint32_t* P = ((jn >> 3) & 1) ? pOa : pEa;
    uint32_t s = 0;
    #pragma unroll
    for (int g = 0; g < 8; ++g) s += P[(g << 8) + idx];
    return (s >> sh) & 0xffffu;
  };

  // ---- fused rowsums ----
  gatherAll(k2P);
  __syncthreads();
  uint32_t r2[2]; r2[0] = gsum(tid); r2[1] = gsum(tid + 512);
  __syncthreads();
  gatherAll(k3P);
  __syncthreads();
  uint32_t r3[2]; r3[0] = gsum(tid); r3[1] = gsum(tid + 512);
  __syncthreads();
  if (lane < 3) gather4All();
  __syncthreads();
  const uint32_t r4v = (tid < NOUT) ? gsum(tid) : 0u;

  // prefetch spk1 row for t=0
  float s1a = out[(size_t)b * NH + tid];
  float s1b = out[(size_t)b * NH + tid + 512];

  for (int t = 0; t < NT; ++t) {
    const size_t rowH = ((size_t)t * NB + b) * (size_t)NH;
    const size_t rowO = ((size_t)t * NB + b) * (size_t)NOUT;

    // ---- layer-1 spikes (precomputed by k_spk1); prefetch next row ----
    bool sA = s1a > 0.5f, sB = s1b > 0.5f;
    {
      int tn = (t + 1 < NT) ? (t + 1) : t;
      size_t rowN = ((size_t)tn * NB + b) * (size_t)NH;
      s1a = out[rowN + tid];
      s1b = out[rowN + tid + 512];
    }
    uint64_t bA = __ballot(sA), bB = __ballot(sB);
    if (lane == 0) wcnt[wave] = (uint32_t)(__popcll(bA) + __popcll(bB));
    __syncthreads();                                         // A
    buildList(bA, bB);
    __syncthreads();                                         // B
    const uint32_t n1 = nT, nl1 = nL; const bool cm1 = cm;
    if (nl1) gatherBig(k2P, nl1);
    __syncthreads();                                         // C

    // ---- layer 2 ----
    {
      float nb = 0.001f * (float)n1;
      #pragma unroll
      for (int c = 0; c < 2; ++c) {
        int j = (c << 9) + tid;
        uint32_t gsv = nl1 ? gsum(j) : 0u;
        uint32_t K = cm1 ? (r2[c] - gsv) : gsv;
        float cur = fmaf(S2C, (float)K, nb);
        float rst = m2[c] > 1.0f ? 1.0f : 0.0f;
        m2[c] = fmaf(0.85f, m2[c], cur) - rst;
        bool sp = (m2[c] - 1.0f) > 0.0f;
        out[O_SPK2 + rowH + j] = sp ? 1.0f : 0.0f;
        if (c == 0) sA = sp; else sB = sp;
      }
    }
    bA = __ballot(sA); bB = __ballot(sB);
    if (lane == 0) wcnt[wave] = (uint32_t)(__popcll(bA) + __popcll(bB));
    __syncthreads();                                         // D
    buildList(bA, bB);
    __syncthreads();                                         // E
    const uint32_t n2 = nT, nl2 = nL; const bool cm2 = cm;
    if (nl2) gatherBig(k3P, nl2);
    __syncthreads();                                         // F

    // ---- layer 3 ----
    {
      float nb = 0.001f * (float)n2;
      #pragma unroll
      for (int c = 0; c < 2; ++c) {
        int j = (c << 9) + tid;
        uint32_t gsv = nl2 ? gsum(j) : 0u;
        uint32_t K = cm2 ? (r3[c] - gsv) : gsv;
        float cur = fmaf(S2C, (float)K, nb);
        float rst = m3[c] > 1.0f ? 1.0f : 0.0f;
        m3[c] = fmaf(0.8f, m3[c], cur) - rst;
        bool sp = (m3[c] - 1.0f) > 0.0f;
        out[O_SPK3 + rowH + j] = sp ? 1.0f : 0.0f;
        if (c == 0) sA = sp; else sB = sp;
      }
    }
    bA = __ballot(sA); bB = __ballot(sB);
    if (lane == 0) wcnt[wave] = (uint32_t)(__popcll(bA) + __popcll(bB));
    __syncthreads();                                         // G
    buildList(bA, bB);
    __syncthreads();                                         // H
    const uint32_t n3 = nT, nl3 = nL; const bool cm3 = cm;

    // ---- layer 4 gather (24-B nibble rows; lanes 0..2 of each group) ----
    if (nl3 && lane < 3) gather4(nl3);
    __syncthreads();                                         // I

    // ---- layer 4 membrane (reset-to-zero) ----
    if (tid < NOUT) {
      uint32_t gsv = nl3 ? gsum(tid) : 0u;
      uint32_t K = cm3 ? (r4v - gsv) : gsv;
      float cur = fmaf(S2C, (float)K, 0.001f * (float)n3);
      float rst = m4 > 1.0f ? 1.0f : 0.0f;
      float bsv = fmaf(0.95f, m4, cur);
      m4 = (rst > 0.0f) ? 0.0f : bsv;
      out[O_SPK4 + rowO + tid] = ((m4 - 1.0f) > 0.0f) ? 1.0f : 0.0f;
      out[O_MEM4 + rowO + tid] = m4;
    }
  }
}
#undef ACCN

extern "C" void kernel_launch(void* const* d_in, const int* in_sizes, int n_in,
                              void* d_out, int out_size, void* d_ws, size_t ws_size,
                              hipStream_t stream)
{
  const float* x  = (const float*)d_in[0];
  const float* w1 = (const float*)d_in[1];
  const float* w2 = (const float*)d_in[2];
  const float* w3 = (const float*)d_in[3];
  const float* w4 = (const float*)d_in[4];
  float* out = (float*)d_out;
  uint8_t* ws = (uint8_t*)d_ws;
  // ids: 524288*2 + 24576 + 131072 + 3276800 = 4481024 -> 17504 blocks
  hipLaunchKernelGGL(k_prep, dim3(17504), dim3(256), 0, stream, x, w1, w2, w3, w4, ws);
  hipLaunchKernelGGL(k_spk1, dim3(256),   dim3(256), 0, stream,
                     (const float*)(ws + WS_XT), (const float*)(ws + WS_Q1T), out);
  hipLaunchKernelGGL(k_main, dim3(256),   dim3(512), 0, stream,
                     ws + WS_K2T, ws + WS_K3T, ws + WS_K4T, out);
}

// Round 8
// 728.714 us; speedup vs baseline: 1.0606x; 1.0606x over previous
//
#include <hip/hip_runtime.h>
#include <stdint.h>

// Problem dims
#define NB  256
#define NT  100
#define NIN 128
#define NH  1024
#define NOUT 35

// d_out float offsets
#define O_SPK2 26214400ull
#define O_SPK3 52428800ull
#define O_SPK4 78643200ull
#define O_MEM4 79539200ull

// d_ws byte offsets (R0 layout)
#define WS_XT   0ull          // 25600*128*4 = 13107200
#define WS_Q1T  13107200ull   // 128*1024*4  = 524288
#define WS_K2T  13631488ull   // 1048576
#define WS_K3T  14680064ull   // 1048576
#define WS_K4T  15728640ull   // 1024*48 = 49152 (padded stride 48)

// scale = (w_max - w_min)/15 computed in python fp64 then cast to fp32
#define S2C ((float)((1.0 - 0.001) / 15.0))
#define S1C ((float)(1.0 / 15.0))

// ------------------------------------------------------------------
// K1: quantize weights -> transposed i8 index matrices + q1T fp32 + xt
// (R0 original, proven)
// ------------------------------------------------------------------
__global__ void k_prep(const float* __restrict__ x, const float* __restrict__ w1,
                       const float* __restrict__ w2, const float* __restrict__ w3,
                       const float* __restrict__ w4, uint8_t* __restrict__ ws)
{
  long long id = (long long)blockIdx.x * 256 + threadIdx.x;
  if (id < 1048576) {                       // k2T[i*1024+j] = k(w2[j][i])
    int i = (int)(id >> 10), j = (int)(id & 1023);
    float wv = w2[(size_t)j * 1024 + i];
    float wc = fminf(fmaxf(wv, 0.001f), 1.0f);
    ws[WS_K2T + id] = (uint8_t)(int)rintf((wc - 0.001f) / S2C);
    return;
  }
  id -= 1048576;
  if (id < 1048576) {                       // k3T
    int i = (int)(id >> 10), j = (int)(id & 1023);
    float wv = w3[(size_t)j * 1024 + i];
    float wc = fminf(fmaxf(wv, 0.001f), 1.0f);
    ws[WS_K3T + id] = (uint8_t)(int)rintf((wc - 0.001f) / S2C);
    return;
  }
  id -= 1048576;
  if (id < 49152) {                         // k4T stride 48, pad j>=35 with 0
    int i = (int)(id / 48), j = (int)(id % 48);
    uint8_t v = 0;
    if (j < NOUT) {
      float wv = w4[(size_t)j * 1024 + i];
      float wc = fminf(fmaxf(wv, 0.001f), 1.0f);
      v = (uint8_t)(int)rintf((wc - 0.001f) / S2C);
    }
    ws[WS_K4T + id] = v;
    return;
  }
  id -= 49152;
  if (id < 131072) {                        // q1T[i*1024+j] = fake_quant(w1[j][i]) fp32
    int i = (int)(id >> 10), j = (int)(id & 1023);
    float wv = w1[(size_t)j * 128 + i];
    float wc = fminf(fmaxf(wv, -0.5f), 0.5f);
    float q = rintf((wc + 0.5f) / S1C) * S1C - 0.5f;
    ((float*)(ws + WS_Q1T))[id] = q;
    return;
  }
  id -= 131072;
  if (id < 3276800) {                       // xt[(t*256+b)*128+i] = x[b][t][i]/15
    int row = (int)(id >> 7), i = (int)(id & 127);
    int tt = row >> 8, bb = row & 255;
    ((float*)(ws + WS_XT))[id] = x[((size_t)bb * NT + tt) * NIN + i] / 15.0f;
  }
}

// ------------------------------------------------------------------
// K2: fused layer-1 GEMM + LIF scan, LDS-staged x, 256 threads x 4
// neurons (R6 version: halves per-CU ds_read vs 512x2). FMA chain
// per neuron ascending-i, bitwise identical.
// ------------------------------------------------------------------
__global__ __launch_bounds__(256, 1) void k_spk1(const float* __restrict__ xt,
                                                 const float* __restrict__ q1T,
                                                 float* __restrict__ out)
{
  __shared__ float xs[25 * 128];        // [tt][i], 12.8 KB
  const int b = blockIdx.x;
  const int tid = threadIdx.x;          // 0..255
  float m[4] = {0.f, 0.f, 0.f, 0.f};

  for (int c = 0; c < 4; ++c) {
    __syncthreads();                    // xs reuse guard
    #pragma unroll
    for (int k = 0; k < 4; ++k) {       // stage 800 float4
      int e = tid + k * 256;
      if (e < 800) {
        int tt = e >> 5, iq = e & 31;
        ((float4*)xs)[e] = *(const float4*)(xt + ((size_t)(c * 25 + tt) * NB + b) * NIN + iq * 4);
      }
    }
    __syncthreads();

    float acc[4][25];
    #pragma unroll
    for (int tt = 0; tt < 25; ++tt) {
      acc[0][tt] = 0.f; acc[1][tt] = 0.f; acc[2][tt] = 0.f; acc[3][tt] = 0.f;
    }
    for (int ib = 0; ib < 16; ++ib) {   // rolled: small I$
      float q0[8], q1v[8], q2v[8], q3v[8];
      #pragma unroll
      for (int u = 0; u < 8; ++u) {
        const float* qp = q1T + (size_t)(ib * 8 + u) * NH + tid;
        q0[u]  = qp[0];
        q1v[u] = qp[256];
        q2v[u] = qp[512];
        q3v[u] = qp[768];
      }
      #pragma unroll
      for (int tt = 0; tt < 25; ++tt) {
        const float4 xa = *(const float4*)&xs[tt * 128 + ib * 8];
        const float4 xb = *(const float4*)&xs[tt * 128 + ib * 8 + 4];
        float xr[8] = {xa.x, xa.y, xa.z, xa.w, xb.x, xb.y, xb.z, xb.w};
        #pragma unroll
        for (int u = 0; u < 8; ++u) {
          acc[0][tt] = fmaf(xr[u], q0[u],  acc[0][tt]);
          acc[1][tt] = fmaf(xr[u], q1v[u], acc[1][tt]);
          acc[2][tt] = fmaf(xr[u], q2v[u], acc[2][tt]);
          acc[3][tt] = fmaf(xr[u], q3v[u], acc[3][tt]);
        }
      }
    }
    // sequential LIF scan (subtract-reset), identical math/order
    #pragma unroll
    for (int tt = 0; tt < 25; ++tt) {
      const int t = c * 25 + tt;
      const size_t row = ((size_t)t * NB + b) * (size_t)NH;
      #pragma unroll
      for (int n = 0; n < 4; ++n) {
        float rst = m[n] > 1.0f ? 1.0f : 0.0f;
        m[n] = fmaf(0.9f, m[n], acc[n][tt]) - rst;
        out[row + n * 256 + tid] = ((m[n] - 1.0f) > 0.0f) ? 1.0f : 0.0f;
      }
    }
  }
}

// ------------------------------------------------------------------
// K3: persistent per-batch-element SNN loop (R6 512-thread structure)
// with CONTIGUOUS-CHUNK, DEPTH-8 gathers: each wave owns a contiguous
// slice of the spike list (adjacent rows -> L2 locality) and keeps 8
// row loads in flight (latency chain ~5 rounds -> ~2-3 per gather).
// Integer partial sums are exact and commutative -> same results.
// ------------------------------------------------------------------
#define ACC(V) do { \
  aE0 += (V).x & 0x00FF00FFu; aO0 += ((V).x >> 8) & 0x00FF00FFu; \
  aE1 += (V).y & 0x00FF00FFu; aO1 += ((V).y >> 8) & 0x00FF00FFu; \
  aE2 += (V).z & 0x00FF00FFu; aO2 += ((V).z >> 8) & 0x00FF00FFu; \
  aE3 += (V).w & 0x00FF00FFu; aO3 += ((V).w >> 8) & 0x00FF00FFu; } while (0)

__global__ __launch_bounds__(512, 1) void k_main(
    const uint8_t* __restrict__ k2T, const uint8_t* __restrict__ k3T,
    const uint8_t* __restrict__ k4T, float* __restrict__ out)
{
  const int b = blockIdx.x;
  const int tid = threadIdx.x;
  const int lane = tid & 63;
  const int wave = tid >> 6;            // 8 gather groups

  __shared__ uint16_t list[1024];
  __shared__ uint4    pEa4[512];        // [g<8][lane*4..+3] packed u16 sums
  __shared__ uint4    pOa4[512];
  __shared__ uint4    wcnt4[2];
  uint32_t* pEa  = (uint32_t*)pEa4;
  uint32_t* pOa  = (uint32_t*)pOa4;
  uint32_t* wcnt = (uint32_t*)wcnt4;

  float m2[2] = {0.f, 0.f}, m3[2] = {0.f, 0.f}, m4 = 0.f;
  uint32_t nT, nL; bool cm;

  // atomic-free list build: register prefix over per-wave counts
  auto buildList = [&](uint64_t bA, uint64_t bB) {
    const uint4 c0 = wcnt4[0], c1 = wcnt4[1];
    nT = c0.x + c0.y + c0.z + c0.w + c1.x + c1.y + c1.z + c1.w;
    cm = nT > 512;
    nL = cm ? (1024u - nT) : nT;
    uint32_t pre = 0;
    pre += (wave > 0) ? c0.x : 0u;  pre += (wave > 1) ? c0.y : 0u;
    pre += (wave > 2) ? c0.z : 0u;  pre += (wave > 3) ? c0.w : 0u;
    pre += (wave > 4) ? c1.x : 0u;  pre += (wave > 5) ? c1.y : 0u;
    pre += (wave > 6) ? c1.z : 0u;
    const uint32_t bs = cm ? ((uint32_t)(wave << 7) - pre) : pre;
    const uint64_t cA = cm ? ~bA : bA;
    const uint64_t cB = cm ? ~bB : bB;
    const uint64_t ltm = (1ull << lane) - 1ull;
    if ((cA >> lane) & 1ull)
      list[bs + (uint32_t)__popcll(cA & ltm)] = (uint16_t)tid;
    if ((cB >> lane) & 1ull)
      list[bs + (uint32_t)__popcll(cA) + (uint32_t)__popcll(cB & ltm)] = (uint16_t)(tid + 512);
  };

  auto gatherBig = [&](const uint8_t* __restrict__ mat, uint32_t nLv) {
    uint32_t aE0=0,aE1=0,aE2=0,aE3=0,aO0=0,aO1=0,aO2=0,aO3=0;
    const uint8_t* bp = mat + (lane << 4);   // 64 lanes x 16B = full 1KB row
    const uint32_t chunk = (nLv + 7) >> 3;
    uint32_t a   = min((uint32_t)wave * chunk, nLv);
    uint32_t end = min(a + chunk, nLv);
    for (; a + 8 <= end; a += 8) {           // 8 loads in flight
      const uint32_t i0 = list[a + 0], i1 = list[a + 1];
      const uint32_t i2 = list[a + 2], i3 = list[a + 3];
      const uint32_t i4 = list[a + 4], i5 = list[a + 5];
      const uint32_t i6 = list[a + 6], i7 = list[a + 7];
      const uint4 v0 = *(const uint4*)(bp + ((size_t)i0 << 10));
      const uint4 v1 = *(const uint4*)(bp + ((size_t)i1 << 10));
      const uint4 v2 = *(const uint4*)(bp + ((size_t)i2 << 10));
      const uint4 v3 = *(const uint4*)(bp + ((size_t)i3 << 10));
      const uint4 v4 = *(const uint4*)(bp + ((size_t)i4 << 10));
      const uint4 v5 = *(const uint4*)(bp + ((size_t)i5 << 10));
      const uint4 v6 = *(const uint4*)(bp + ((size_t)i6 << 10));
      const uint4 v7 = *(const uint4*)(bp + ((size_t)i7 << 10));
      ACC(v0); ACC(v1); ACC(v2); ACC(v3);
      ACC(v4); ACC(v5); ACC(v6); ACC(v7);
    }
    for (; a < end; ++a) {
      const uint32_t i0 = list[a];
      const uint4 v0 = *(const uint4*)(bp + ((size_t)i0 << 10));
      ACC(v0);
    }
    const int basei = (wave << 8) + (lane << 2);
    *(uint4*)&pEa[basei] = make_uint4(aE0, aE1, aE2, aE3);
    *(uint4*)&pOa[basei] = make_uint4(aO0, aO1, aO2, aO3);
  };

  auto gatherAll = [&](const uint8_t* __restrict__ mat) {   // all 1024 rows
    uint32_t aE0=0,aE1=0,aE2=0,aE3=0,aO0=0,aO1=0,aO2=0,aO3=0;
    const uint8_t* bp = mat + (lane << 4);
    const uint32_t beg = (uint32_t)wave << 7;                // 128 rows/wave
    for (uint32_t a = beg; a < beg + 128u; a += 8) {
      #pragma unroll
      for (int k = 0; k < 8; ++k) {
        const uint4 v = *(const uint4*)(bp + ((size_t)(a + k) << 10));
        ACC(v);
      }
    }
    const int basei = (wave << 8) + (lane << 2);
    *(uint4*)&pEa[basei] = make_uint4(aE0, aE1, aE2, aE3);
    *(uint4*)&pOa[basei] = make_uint4(aO0, aO1, aO2, aO3);
  };

  auto gather4 = [&](uint32_t nLv) {         // k4T, 48-B rows, lanes 0..2
    uint32_t aE0=0,aE1=0,aE2=0,aE3=0,aO0=0,aO1=0,aO2=0,aO3=0;
    const uint8_t* bp = k4T + (lane << 4);
    const uint32_t chunk = (nLv + 7) >> 3;
    uint32_t a   = min((uint32_t)wave * chunk, nLv);
    uint32_t end = min(a + chunk, nLv);
    for (; a + 8 <= end; a += 8) {
      const uint32_t i0 = list[a + 0], i1 = list[a + 1];
      const uint32_t i2 = list[a + 2], i3 = list[a + 3];
      const uint32_t i4 = list[a + 4], i5 = list[a + 5];
      const uint32_t i6 = list[a + 6], i7 = list[a + 7];
      const uint4 v0 = *(const uint4*)(bp + (size_t)i0 * 48u);
      const uint4 v1 = *(const uint4*)(bp + (size_t)i1 * 48u);
      const uint4 v2 = *(const uint4*)(bp + (size_t)i2 * 48u);
      const uint4 v3 = *(const uint4*)(bp + (size_t)i3 * 48u);
      const uint4 v4 = *(const uint4*)(bp + (size_t)i4 * 48u);
      const uint4 v5 = *(const uint4*)(bp + (size_t)i5 * 48u);
      const uint4 v6 = *(const uint4*)(bp + (size_t)i6 * 48u);
      const uint4 v7 = *(const uint4*)(bp + (size_t)i7 * 48u);
      ACC(v0); ACC(v1); ACC(v2); ACC(v3);
      ACC(v4); ACC(v5); ACC(v6); ACC(v7);
    }
    for (; a < end; ++a) {
      const uint32_t i0 = list[a];
      const uint4 v0 = *(const uint4*)(bp + (size_t)i0 * 48u);
      ACC(v0);
    }
    const int basei = (wave << 8) + (lane << 2);
    *(uint4*)&pEa[basei] = make_uint4(aE0, aE1, aE2, aE3);
    *(uint4*)&pOa[basei] = make_uint4(aO0, aO1, aO2, aO3);
  };

  auto gather4All = [&]() {
    uint32_t aE0=0,aE1=0,aE2=0,aE3=0,aO0=0,aO1=0,aO2=0,aO3=0;
    const uint8_t* bp = k4T + (lane << 4);
    const uint32_t beg = (uint32_t)wave << 7;
    for (uint32_t a = beg; a < beg + 128u; a += 8) {
      #pragma unroll
      for (int k = 0; k < 8; ++k) {
        const uint4 v = *(const uint4*)(bp + (size_t)(a + k) * 48u);
        ACC(v);
      }
    }
    const int basei = (wave << 8) + (lane << 2);
    *(uint4*)&pEa[basei] = make_uint4(aE0, aE1, aE2, aE3);
    *(uint4*)&pOa[basei] = make_uint4(aO0, aO1, aO2, aO3);
  };

  // packed-u16 sum over 8 groups (fields can't carry: max 15360 < 2^16)
  auto gsum = [&](int jn) -> uint32_t {
    const int w = jn >> 2, sh = (jn & 2) << 3;
    const uint32_t* P = (jn & 1) ? pOa : pEa;
    uint32_t s = 0;
    #pragma unroll
    for (int g = 0; g < 8; ++g) s += P[(g << 8) + w];
    return (s >> sh) & 0xffffu;
  };

  // ---- fused rowsums (replaces k_rowsum) ----
  gatherAll(k2T);
  __syncthreads();
  uint32_t r2[2]; r2[0] = gsum(tid); r2[1] = gsum(tid + 512);
  __syncthreads();
  gatherAll(k3T);
  __syncthreads();
  uint32_t r3[2]; r3[0] = gsum(tid); r3[1] = gsum(tid + 512);
  __syncthreads();
  if (lane < 3) gather4All();
  __syncthreads();
  const uint32_t r4v = (tid < NOUT) ? gsum(tid) : 0u;

  // prefetch spk1 row for t=0
  float s1a = out[(size_t)b * NH + tid];
  float s1b = out[(size_t)b * NH + tid + 512];

  for (int t = 0; t < NT; ++t) {
    const size_t rowH = ((size_t)t * NB + b) * (size_t)NH;
    const size_t rowO = ((size_t)t * NB + b) * (size_t)NOUT;

    // ---- layer-1 spikes (precomputed by k_spk1); prefetch next row ----
    bool sA = s1a > 0.5f, sB = s1b > 0.5f;
    {
      int tn = (t + 1 < NT) ? (t + 1) : t;
      size_t rowN = ((size_t)tn * NB + b) * (size_t)NH;
      s1a = out[rowN + tid];
      s1b = out[rowN + tid + 512];
    }
    uint64_t bA = __ballot(sA), bB = __ballot(sB);
    if (lane == 0) wcnt[wave] = (uint32_t)(__popcll(bA) + __popcll(bB));
    __syncthreads();                                         // A
    buildList(bA, bB);
    __syncthreads();                                         // B
    const uint32_t n1 = nT, nl1 = nL; const bool cm1 = cm;
    if (nl1) gatherBig(k2T, nl1);
    __syncthreads();                                         // C

    // ---- layer 2 ----
    {
      float nb = 0.001f * (float)n1;
      #pragma unroll
      for (int c = 0; c < 2; ++c) {
        int j = (c << 9) + tid;
        uint32_t gsv = nl1 ? gsum(j) : 0u;
        uint32_t K = cm1 ? (r2[c] - gsv) : gsv;
        float cur = fmaf(S2C, (float)K, nb);
        float rst = m2[c] > 1.0f ? 1.0f : 0.0f;
        m2[c] = fmaf(0.85f, m2[c], cur) - rst;
        bool sp = (m2[c] - 1.0f) > 0.0f;
        out[O_SPK2 + rowH + j] = sp ? 1.0f : 0.0f;
        if (c == 0) sA = sp; else sB = sp;
      }
    }
    bA = __ballot(sA); bB = __ballot(sB);
    if (lane == 0) wcnt[wave] = (uint32_t)(__popcll(bA) + __popcll(bB));
    __syncthreads();                                         // D
    buildList(bA, bB);
    __syncthreads();                                         // E
    const uint32_t n2 = nT, nl2 = nL; const bool cm2 = cm;
    if (nl2) gatherBig(k3T, nl2);
    __syncthreads();                                         // F

    // ---- layer 3 ----
    {
      float nb = 0.001f * (float)n2;
      #pragma unroll
      for (int c = 0; c < 2; ++c) {
        int j = (c << 9) + tid;
        uint32_t gsv = nl2 ? gsum(j) : 0u;
        uint32_t K = cm2 ? (r3[c] - gsv) : gsv;
        float cur = fmaf(S2C, (float)K, nb);
        float rst = m3[c] > 1.0f ? 1.0f : 0.0f;
        m3[c] = fmaf(0.8f, m3[c], cur) - rst;
        bool sp = (m3[c] - 1.0f) > 0.0f;
        out[O_SPK3 + rowH + j] = sp ? 1.0f : 0.0f;
        if (c == 0) sA = sp; else sB = sp;
      }
    }
    bA = __ballot(sA); bB = __ballot(sB);
    if (lane == 0) wcnt[wave] = (uint32_t)(__popcll(bA) + __popcll(bB));
    __syncthreads();                                         // G
    buildList(bA, bB);
    __syncthreads();                                         // H
    const uint32_t n3 = nT, nl3 = nL; const bool cm3 = cm;

    // ---- layer 4 gather (48-B padded rows; lanes 0..2 of each group) ----
    if (nl3 && lane < 3) gather4(nl3);
    __syncthreads();                                         // I

    // ---- layer 4 membrane (reset-to-zero) ----
    if (tid < NOUT) {
      uint32_t gsv = nl3 ? gsum(tid) : 0u;
      uint32_t K = cm3 ? (r4v - gsv) : gsv;
      float cur = fmaf(S2C, (float)K, 0.001f * (float)n3);
      float rst = m4 > 1.0f ? 1.0f : 0.0f;
      float bsv = fmaf(0.95f, m4, cur);
      m4 = (rst > 0.0f) ? 0.0f : bsv;
      out[O_SPK4 + rowO + tid] = ((m4 - 1.0f) > 0.0f) ? 1.0f : 0.0f;
      out[O_MEM4 + rowO + tid] = m4;
    }
  }
}
#undef ACC

extern "C" void kernel_launch(void* const* d_in, const int* in_sizes, int n_in,
                              void* d_out, int out_size, void* d_ws, size_t ws_size,
                              hipStream_t stream)
{
  const float* x  = (const float*)d_in[0];
  const float* w1 = (const float*)d_in[1];
  const float* w2 = (const float*)d_in[2];
  const float* w3 = (const float*)d_in[3];
  const float* w4 = (const float*)d_in[4];
  float* out = (float*)d_out;
  uint8_t* ws = (uint8_t*)d_ws;
  hipLaunchKernelGGL(k_prep, dim3(21696), dim3(256), 0, stream, x, w1, w2, w3, w4, ws);
  hipLaunchKernelGGL(k_spk1, dim3(256),   dim3(256), 0, stream,
                     (const float*)(ws + WS_XT), (const float*)(ws + WS_Q1T), out);
  hipLaunchKernelGGL(k_main, dim3(256),   dim3(512), 0, stream,
                     ws + WS_K2T, ws + WS_K3T, ws + WS_K4T, out);
}